// Round 6
// baseline (223.614 us; speedup 1.0000x reference)
//
#include <hip/hip_runtime.h>

#define NUM_USERS 100000
#define NUM_ITEMS 100000
#define EMB_DIM   128
#define NUM_EDGES 600000
#define NN        200000   // N_NODES

#define SCAN_B  256
#define SCAN_NB ((NN + SCAN_B - 1) / SCAN_B)   // 782

typedef __attribute__((ext_vector_type(8))) unsigned short ushort8_t;
typedef __attribute__((ext_vector_type(4))) float float4_t;

// bf16 helpers (RNE rounding)
__device__ inline float bf2f(unsigned short u) {
    unsigned int x = ((unsigned int)u) << 16;
    return __builtin_bit_cast(float, x);
}
__device__ inline unsigned short f2bf(float f) {
    unsigned int x = __builtin_bit_cast(unsigned int, f);
    x += 0x7fffu + ((x >> 16) & 1u);   // round-to-nearest-even
    return (unsigned short)(x >> 16);
}

// ---------- degree count (in-degree over col) ----------
__global__ void k_count(const int* __restrict__ col, int* __restrict__ deg) {
    int e = blockIdx.x * blockDim.x + threadIdx.x;
    if (e < NUM_EDGES) atomicAdd(&deg[col[e]], 1);
}

// ---------- scan part 1 + deg_inv_sqrt fused ----------
__global__ void k_scan1(const int* __restrict__ deg, int* __restrict__ rp,
                        int* __restrict__ bsum, float* __restrict__ dis) {
    __shared__ int s[SCAN_B];
    int tid = threadIdx.x;
    int i = blockIdx.x * SCAN_B + tid;
    int v = (i < NN) ? deg[i] : 0;
    s[tid] = v;
    __syncthreads();
    for (int off = 1; off < SCAN_B; off <<= 1) {
        int t = (tid >= off) ? s[tid - off] : 0;
        __syncthreads();
        s[tid] += t;
        __syncthreads();
    }
    if (i < NN) {
        rp[i]  = s[tid] - v;                    // exclusive within block
        dis[i] = (v > 0) ? 1.0f / sqrtf((float)v) : 0.0f;
    }
    if (tid == SCAN_B - 1) bsum[blockIdx.x] = s[tid];
}

__global__ void k_scan2(int* __restrict__ bsum) {
    __shared__ int s[1024];
    int tid = threadIdx.x;
    int v = (tid < SCAN_NB) ? bsum[tid] : 0;
    s[tid] = v;
    __syncthreads();
    for (int off = 1; off < 1024; off <<= 1) {
        int t = (tid >= off) ? s[tid - off] : 0;
        __syncthreads();
        s[tid] += t;
        __syncthreads();
    }
    if (tid < SCAN_NB) bsum[tid] = s[tid] - v;
}

__global__ void k_scan3(int* __restrict__ rp, const int* __restrict__ bsum) {
    int i = blockIdx.x * SCAN_B + threadIdx.x;
    if (i < NN) rp[i] += bsum[blockIdx.x];
    if (i == 0) rp[NN] = NUM_EDGES;
}

// ---------- CSR fill, packed (src, coef) ----------
__global__ void k_fill(const int* __restrict__ row, const int* __restrict__ col,
                       const float* __restrict__ dis, const int* __restrict__ rp,
                       int* __restrict__ cursor, int2* __restrict__ csr) {
    int e = blockIdx.x * blockDim.x + threadIdx.x;
    if (e >= NUM_EDGES) return;
    int r = row[e], c = col[e];
    int p = rp[c] + atomicAdd(&cursor[c], 1);
    csr[p] = make_int2(r, __builtin_bit_cast(int, dis[r] * dis[c]));
}

// ---------- layer 0: y1 = A * emb (f32 gather), store bf16 ----------
__global__ void k_gath0(const float* __restrict__ emb, const int* __restrict__ rp,
                        const int2* __restrict__ csr, ushort* __restrict__ xn) {
    int t    = blockIdx.x * blockDim.x + threadIdx.x;
    int node = t >> 4;
    int lane = t & 15;
    if (node >= NN) return;
    int beg = rp[node], end = rp[node + 1];
    float a[8] = {0, 0, 0, 0, 0, 0, 0, 0};
    const int bd = lane * 8;
    for (int k = beg; k < end; k += 4) {
        const int last = end - 1;
        const int k1 = min(k + 1, last), k2 = min(k + 2, last), k3 = min(k + 3, last);
        const int2 e0 = csr[k], e1 = csr[k1], e2 = csr[k2], e3 = csr[k3];
        const float c0 = __builtin_bit_cast(float, e0.y);
        const float c1 = (k + 1 <= last) ? __builtin_bit_cast(float, e1.y) : 0.0f;
        const float c2 = (k + 2 <= last) ? __builtin_bit_cast(float, e2.y) : 0.0f;
        const float c3 = (k + 3 <= last) ? __builtin_bit_cast(float, e3.y) : 0.0f;
        const float4 u0 = *reinterpret_cast<const float4*>(emb + (size_t)e0.x * EMB_DIM + bd);
        const float4 u1 = *reinterpret_cast<const float4*>(emb + (size_t)e1.x * EMB_DIM + bd);
        const float4 u2 = *reinterpret_cast<const float4*>(emb + (size_t)e2.x * EMB_DIM + bd);
        const float4 u3 = *reinterpret_cast<const float4*>(emb + (size_t)e3.x * EMB_DIM + bd);
        const float4 w0 = *reinterpret_cast<const float4*>(emb + (size_t)e0.x * EMB_DIM + bd + 4);
        const float4 w1 = *reinterpret_cast<const float4*>(emb + (size_t)e1.x * EMB_DIM + bd + 4);
        const float4 w2 = *reinterpret_cast<const float4*>(emb + (size_t)e2.x * EMB_DIM + bd + 4);
        const float4 w3 = *reinterpret_cast<const float4*>(emb + (size_t)e3.x * EMB_DIM + bd + 4);
        a[0] += c0 * u0.x + c1 * u1.x + c2 * u2.x + c3 * u3.x;
        a[1] += c0 * u0.y + c1 * u1.y + c2 * u2.y + c3 * u3.y;
        a[2] += c0 * u0.z + c1 * u1.z + c2 * u2.z + c3 * u3.z;
        a[3] += c0 * u0.w + c1 * u1.w + c2 * u2.w + c3 * u3.w;
        a[4] += c0 * w0.x + c1 * w1.x + c2 * w2.x + c3 * w3.x;
        a[5] += c0 * w0.y + c1 * w1.y + c2 * w2.y + c3 * w3.y;
        a[6] += c0 * w0.z + c1 * w1.z + c2 * w2.z + c3 * w3.z;
        a[7] += c0 * w0.w + c1 * w1.w + c2 * w2.w + c3 * w3.w;
    }
    ushort8_t w;
#pragma unroll
    for (int j = 0; j < 8; ++j) w[j] = f2bf(a[j]);
    __builtin_nontemporal_store(w,
        reinterpret_cast<ushort8_t*>(xn + (size_t)node * EMB_DIM + bd));
}

// ---------- layer 1: y2 = A * x1 (bf16), store bf16 ----------
__global__ void k_gath(const ushort* __restrict__ x, const int* __restrict__ rp,
                       const int2* __restrict__ csr, ushort* __restrict__ xn) {
    int t    = blockIdx.x * blockDim.x + threadIdx.x;
    int node = t >> 4;
    int lane = t & 15;
    if (node >= NN) return;
    int beg = rp[node], end = rp[node + 1];
    float a[8] = {0, 0, 0, 0, 0, 0, 0, 0};
    const int bd = lane * 8;
    for (int k = beg; k < end; k += 4) {
        const int last = end - 1;
        const int k1 = min(k + 1, last), k2 = min(k + 2, last), k3 = min(k + 3, last);
        const int2 e0 = csr[k], e1 = csr[k1], e2 = csr[k2], e3 = csr[k3];
        const float c0 = __builtin_bit_cast(float, e0.y);
        const float c1 = (k + 1 <= last) ? __builtin_bit_cast(float, e1.y) : 0.0f;
        const float c2 = (k + 2 <= last) ? __builtin_bit_cast(float, e2.y) : 0.0f;
        const float c3 = (k + 3 <= last) ? __builtin_bit_cast(float, e3.y) : 0.0f;
        const ushort8_t v0 = *reinterpret_cast<const ushort8_t*>(x + (size_t)e0.x * EMB_DIM + bd);
        const ushort8_t v1 = *reinterpret_cast<const ushort8_t*>(x + (size_t)e1.x * EMB_DIM + bd);
        const ushort8_t v2 = *reinterpret_cast<const ushort8_t*>(x + (size_t)e2.x * EMB_DIM + bd);
        const ushort8_t v3 = *reinterpret_cast<const ushort8_t*>(x + (size_t)e3.x * EMB_DIM + bd);
#pragma unroll
        for (int j = 0; j < 8; ++j)
            a[j] += c0 * bf2f(v0[j]) + c1 * bf2f(v1[j]) +
                    c2 * bf2f(v2[j]) + c3 * bf2f(v3[j]);
    }
    ushort8_t w;
#pragma unroll
    for (int j = 0; j < 8; ++j) w[j] = f2bf(a[j]);
    __builtin_nontemporal_store(w,
        reinterpret_cast<ushort8_t*>(xn + (size_t)node * EMB_DIM + bd));
}

// ---------- final: y3 = A * x2;  out = (emb + x1 + x2 + y3) * 0.25 ----------
__global__ void k_final(const ushort* __restrict__ x2, const int* __restrict__ rp,
                        const int2* __restrict__ csr,
                        const float* __restrict__ emb, const ushort* __restrict__ x1,
                        float* __restrict__ out) {
    int t    = blockIdx.x * blockDim.x + threadIdx.x;
    int node = t >> 4;
    int lane = t & 15;
    if (node >= NN) return;
    int beg = rp[node], end = rp[node + 1];
    float a[8] = {0, 0, 0, 0, 0, 0, 0, 0};
    const int bd = lane * 8;
    for (int k = beg; k < end; k += 4) {
        const int last = end - 1;
        const int k1 = min(k + 1, last), k2 = min(k + 2, last), k3 = min(k + 3, last);
        const int2 e0 = csr[k], e1 = csr[k1], e2 = csr[k2], e3 = csr[k3];
        const float c0 = __builtin_bit_cast(float, e0.y);
        const float c1 = (k + 1 <= last) ? __builtin_bit_cast(float, e1.y) : 0.0f;
        const float c2 = (k + 2 <= last) ? __builtin_bit_cast(float, e2.y) : 0.0f;
        const float c3 = (k + 3 <= last) ? __builtin_bit_cast(float, e3.y) : 0.0f;
        const ushort8_t v0 = *reinterpret_cast<const ushort8_t*>(x2 + (size_t)e0.x * EMB_DIM + bd);
        const ushort8_t v1 = *reinterpret_cast<const ushort8_t*>(x2 + (size_t)e1.x * EMB_DIM + bd);
        const ushort8_t v2 = *reinterpret_cast<const ushort8_t*>(x2 + (size_t)e2.x * EMB_DIM + bd);
        const ushort8_t v3 = *reinterpret_cast<const ushort8_t*>(x2 + (size_t)e3.x * EMB_DIM + bd);
#pragma unroll
        for (int j = 0; j < 8; ++j)
            a[j] += c0 * bf2f(v0[j]) + c1 * bf2f(v1[j]) +
                    c2 * bf2f(v2[j]) + c3 * bf2f(v3[j]);
    }
    const size_t o = (size_t)node * EMB_DIM + bd;
    const float4    e0 = *reinterpret_cast<const float4*>(emb + o);
    const float4    e1 = *reinterpret_cast<const float4*>(emb + o + 4);
    const ushort8_t w1 = *reinterpret_cast<const ushort8_t*>(x1 + o);
    const ushort8_t w2 = *reinterpret_cast<const ushort8_t*>(x2 + o);
    float4_t r0, r1;
    r0[0] = (e0.x + bf2f(w1[0]) + bf2f(w2[0]) + a[0]) * 0.25f;
    r0[1] = (e0.y + bf2f(w1[1]) + bf2f(w2[1]) + a[1]) * 0.25f;
    r0[2] = (e0.z + bf2f(w1[2]) + bf2f(w2[2]) + a[2]) * 0.25f;
    r0[3] = (e0.w + bf2f(w1[3]) + bf2f(w2[3]) + a[3]) * 0.25f;
    r1[0] = (e1.x + bf2f(w1[4]) + bf2f(w2[4]) + a[4]) * 0.25f;
    r1[1] = (e1.y + bf2f(w1[5]) + bf2f(w2[5]) + a[5]) * 0.25f;
    r1[2] = (e1.z + bf2f(w1[6]) + bf2f(w2[6]) + a[6]) * 0.25f;
    r1[3] = (e1.w + bf2f(w1[7]) + bf2f(w2[7]) + a[7]) * 0.25f;
    // out is never re-read: nontemporal keeps emb/x1/x2 L3-resident for the gather
    __builtin_nontemporal_store(r0, reinterpret_cast<float4_t*>(out + o));
    __builtin_nontemporal_store(r1, reinterpret_cast<float4_t*>(out + o) + 1);
}

extern "C" void kernel_launch(void* const* d_in, const int* in_sizes, int n_in,
                              void* d_out, int out_size, void* d_ws, size_t ws_size,
                              hipStream_t stream) {
    const int*   edges = (const int*)d_in[0];
    const int*   row   = edges;               // edge_index[0]
    const int*   col   = edges + NUM_EDGES;   // edge_index[1]
    const float* emb   = (const float*)d_in[1];
    float*       out   = (float*)d_out;

    char*  ws  = (char*)d_ws;
    size_t off = 0;
    auto alloc = [&](size_t bytes) {
        void* p = ws + off;
        off += (bytes + 255) & ~(size_t)255;
        return p;
    };
    ushort* x1     = (ushort*)alloc(sizeof(ushort) * (size_t)NN * EMB_DIM); // 51.2 MB
    ushort* x2     = (ushort*)alloc(sizeof(ushort) * (size_t)NN * EMB_DIM); // 51.2 MB
    int*    deg    = (int*)   alloc(sizeof(int)   * NN);        // deg+cursor adjacent:
    int*    cursor = (int*)   alloc(sizeof(int)   * NN);        // single memset below
    float*  dis    = (float*) alloc(sizeof(float) * NN);
    int*    rp     = (int*)   alloc(sizeof(int)   * (NN + 1));
    int2*   csr    = (int2*)  alloc(sizeof(int2)  * NUM_EDGES);             // 4.8 MB
    int*    bsum   = (int*)   alloc(sizeof(int)   * 1024);

    (void)hipMemsetAsync(deg, 0, sizeof(int) * NN * 2, stream);  // deg + cursor

    const int EB = (NUM_EDGES + 255) / 256;
    k_count<<<EB, 256, 0, stream>>>(col, deg);
    k_scan1<<<SCAN_NB, SCAN_B, 0, stream>>>(deg, rp, bsum, dis);
    k_scan2<<<1, 1024, 0, stream>>>(bsum);
    k_scan3<<<SCAN_NB, SCAN_B, 0, stream>>>(rp, bsum);
    k_fill<<<EB, 256, 0, stream>>>(row, col, dis, rp, cursor, csr);

    const int LB = (int)(((size_t)NN * 16) / 256);            // 12500
    k_gath0<<<LB, 256, 0, stream>>>(emb, rp, csr, x1);
    k_gath <<<LB, 256, 0, stream>>>(x1, rp, csr, x2);
    k_final<<<LB, 256, 0, stream>>>(x2, rp, csr, emb, x1, out);
}